// Round 1
// 199.279 us; speedup vs baseline: 1.0021x; 1.0021x over previous
//
#include <hip/hip_runtime.h>
#include <math.h>

#define NTIME 20
#define V 128
#define F 128
constexpr float ALPHA = 0.2f;

typedef float f32x4 __attribute__((ext_vector_type(4)));

// ---------------- kernel 0: Wa[s] = W @ a_s  (128x128 each, f32) ----------------
__global__ __launch_bounds__(128) void k_wa(const float* __restrict__ W,
                                            const float* __restrict__ a,
                                            float* __restrict__ Wa) {
  const int i = blockIdx.x;
  const int s = blockIdx.y;
  const int k = threadIdx.x;
  __shared__ float wrow[F];
  wrow[k] = W[i * F + k];
  __syncthreads();
  const float* as = a + s * F * F;
  float acc = 0.f;
#pragma unroll 8
  for (int m = 0; m < F; ++m) acc += wrow[m] * as[m * F + k];
  Wa[(s * F + i) * F + k] = acc;
}

// ---------------- kernel 1: [Wh|E1|E2] = h @ [W|Wa1|Wa2] ----------------
// 32x64 tiles -> 480 blocks (was 240 < 256 CUs). ~2 blocks/CU, 48 KB LDS.
__global__ __launch_bounds__(256) void k_gemm(const float* __restrict__ h,
                                              const float* __restrict__ W,
                                              const float* __restrict__ Wa,
                                              float* __restrict__ Wh,
                                              float* __restrict__ E1,
                                              float* __restrict__ E2) {
  __shared__ float Alds[32][129];
  __shared__ float Blds[128][64];
  const int tid = threadIdx.x;
  const int rb = blockIdx.x * 32;
  const int matc = blockIdx.y >> 1;
  const int cb = (blockIdx.y & 1) * 64;

#pragma unroll
  for (int p = 0; p < 4; ++p) {
    int id = tid + p * 256;
    int row = id >> 5;
    int c0 = (id & 31) * 4;
    float4 v = *reinterpret_cast<const float4*>(&h[(rb + row) * F + c0]);
    Alds[row][c0 + 0] = v.x; Alds[row][c0 + 1] = v.y;
    Alds[row][c0 + 2] = v.z; Alds[row][c0 + 3] = v.w;
  }
  const float* src = (matc == 0) ? W : (Wa + (matc - 1) * F * F);
#pragma unroll
  for (int p = 0; p < 8; ++p) {
    int id = tid + p * 256;
    int k = id >> 4;
    int c0 = (id & 15) * 4;
    float4 v = *reinterpret_cast<const float4*>(&src[k * F + cb + c0]);
    Blds[k][c0 + 0] = v.x; Blds[k][c0 + 1] = v.y;
    Blds[k][c0 + 2] = v.z; Blds[k][c0 + 3] = v.w;
  }
  __syncthreads();

  const int tx = tid & 15;      // 4-col group within 64 cols
  const int ty = tid >> 4;      // 2-row group within 32 rows
  float acc[2][4] = {};
#pragma unroll 4
  for (int k = 0; k < 128; ++k) {
    float4 bv = *reinterpret_cast<const float4*>(&Blds[k][tx * 4]);
    float a0 = Alds[ty * 2 + 0][k];
    float a1 = Alds[ty * 2 + 1][k];
    acc[0][0] += a0 * bv.x; acc[0][1] += a0 * bv.y; acc[0][2] += a0 * bv.z; acc[0][3] += a0 * bv.w;
    acc[1][0] += a1 * bv.x; acc[1][1] += a1 * bv.y; acc[1][2] += a1 * bv.z; acc[1][3] += a1 * bv.w;
  }

  float* Dp = (matc == 0) ? Wh : ((matc == 1) ? E1 : E2);
  const int gr0 = rb + ty * 2;
  const int c0 = cb + tx * 4;
#pragma unroll
  for (int i = 0; i < 2; ++i) {
    float4 v;
    v.x = acc[i][0]; v.y = acc[i][1]; v.z = acc[i][2]; v.w = acc[i][3];
    *reinterpret_cast<float4*>(&Dp[(gr0 + i) * F + c0]) = v;
  }
}

// ------- kernel 2: fused attention, TWO rows (same t) per block -------
// Branchless pass A (gate by mask-derived 0/1 multiply, loads always issued
// -> deep vmcnt batching). Pass B: gates from ballot masks (no adj reload),
// uni-branch hoisted, nontemporal att stores (168 MB stream, never re-read).
__global__ __launch_bounds__(256, 5) void k_attn(const float* __restrict__ Wh,
                                                 const float* __restrict__ E1,
                                                 const float* __restrict__ E2,
                                                 const float* __restrict__ adj,
                                                 float* __restrict__ out,
                                                 float* __restrict__ att) {
  __shared__ float sA[2][4][F];
  __shared__ float hA[2][4][F];
  __shared__ float invA[2][F];
  __shared__ float uniA[2];

  const int r0 = blockIdx.x * 2;          // even, so r0 and r0+1 share t
  const int r1 = r0 + 1;
  const int t = r0 >> 7;
  const int b0 = r0 & 127;
  const int w = threadIdx.x >> 6;
  const int lane = threadIdx.x & 63;
  const int fc = lane * 2;
  const int j0 = w * 32;

  const float* E2t = E2 + t * V * F;
  const float* Wht = Wh + t * V * F;
  const float* adj0 = adj + b0 * V;
  const float* adj1 = adj0 + V;

  // hoist adj for this wave's strip into two 32-bit masks (bit jj <-> j0+jj)
  const bool in32 = lane < 32;
  const unsigned long long Ma = __ballot(in32 ? (adj0[j0 + (lane & 31)] > 0.f) : false);
  const unsigned long long Mb = __ballot(in32 ? (adj1[j0 + (lane & 31)] > 0.f) : false);
  const unsigned ma32 = (unsigned)Ma;
  const unsigned mb32 = (unsigned)Mb;

  const float2 e1a = *reinterpret_cast<const float2*>(E1 + r0 * F + fc);
  const float2 e1b = *reinterpret_cast<const float2*>(E1 + r1 * F + fc);

  // ---- pass A: branchless gated accumulate ----
  float sa0 = 0.f, sa1 = 0.f, ha0 = 0.f, ha1 = 0.f;
  float sb0 = 0.f, sb1 = 0.f, hb0 = 0.f, hb1 = 0.f;
#pragma unroll 8
  for (int jj = 0; jj < 32; ++jj) {
    const int j = j0 + jj;
    const float2 e2 = *reinterpret_cast<const float2*>(E2t + j * F + fc);
    const float2 wv = *reinterpret_cast<const float2*>(Wht + j * F + fc);
    const float ga = (float)((ma32 >> jj) & 1u);
    const float gb = (float)((mb32 >> jj) & 1u);
    float x0 = e1a.x + e2.x, x1 = e1a.y + e2.y;
    x0 = fmaxf(x0, ALPHA * x0);
    x1 = fmaxf(x1, ALPHA * x1);
    float p0 = __expf(x0) * ga, p1 = __expf(x1) * ga;
    sa0 += p0; sa1 += p1;
    ha0 = fmaf(p0, wv.x, ha0); ha1 = fmaf(p1, wv.y, ha1);
    x0 = e1b.x + e2.x; x1 = e1b.y + e2.y;
    x0 = fmaxf(x0, ALPHA * x0);
    x1 = fmaxf(x1, ALPHA * x1);
    p0 = __expf(x0) * gb; p1 = __expf(x1) * gb;
    sb0 += p0; sb1 += p1;
    hb0 = fmaf(p0, wv.x, hb0); hb1 = fmaf(p1, wv.y, hb1);
  }
  sA[0][w][fc] = sa0; sA[0][w][fc + 1] = sa1;
  hA[0][w][fc] = ha0; hA[0][w][fc + 1] = ha1;
  sA[1][w][fc] = sb0; sA[1][w][fc + 1] = sb1;
  hA[1][w][fc] = hb0; hA[1][w][fc + 1] = hb1;
  __syncthreads();

  // ---- reduce: wave 0 -> row 0, wave 1 -> row 1 (parallel) ----
  if (w < 2) {
    const int row = w;
    const int r = r0 + row;
    const float S0 = sA[row][0][fc] + sA[row][1][fc] + sA[row][2][fc] + sA[row][3][fc];
    const float S1 = sA[row][0][fc + 1] + sA[row][1][fc + 1] + sA[row][2][fc + 1] + sA[row][3][fc + 1];
    const bool uni = (S0 == 0.f);         // all-masked row -> uniform 1/V
    const float inv0 = uni ? (1.f / (float)V) : (1.f / S0);
    const float inv1 = uni ? (1.f / (float)V) : (1.f / S1);
    invA[row][fc] = inv0; invA[row][fc + 1] = inv1;
    if (lane == 0) uniA[row] = uni ? 1.f : 0.f;

    float H0, H1;
    if (uni) {
      H0 = 0.f; H1 = 0.f;
      for (int j = 0; j < V; ++j) {
        float2 wv = *reinterpret_cast<const float2*>(Wht + j * F + fc);
        H0 += wv.x; H1 += wv.y;
      }
      H0 *= inv0; H1 *= inv1;
    } else {
      H0 = (hA[row][0][fc] + hA[row][1][fc] + hA[row][2][fc] + hA[row][3][fc]) * inv0;
      H1 = (hA[row][0][fc + 1] + hA[row][1][fc + 1] + hA[row][2][fc + 1] + hA[row][3][fc + 1]) * inv1;
    }
    float2 ov;
    ov.x = H0 > 0.f ? H0 : __expf(H0) - 1.f;
    ov.y = H1 > 0.f ? H1 : __expf(H1) - 1.f;
    *reinterpret_cast<float2*>(out + r * F + fc) = ov;
  }
  __syncthreads();

  // ---- pass B: one e2q load feeds 2 stores (rows 0 and 1) ----
  const int jh = lane >> 5;
  const int f4 = (lane & 31) * 4;
  const float4 e1qa = *reinterpret_cast<const float4*>(E1 + r0 * F + f4);
  const float4 e1qb = *reinterpret_cast<const float4*>(E1 + r1 * F + f4);
  const float4 invqa = *reinterpret_cast<const float4*>(&invA[0][f4]);
  const float4 invqb = *reinterpret_cast<const float4*>(&invA[1][f4]);
  const bool ua = uniA[0] != 0.f;
  const bool ub = uniA[1] != 0.f;
  float* attb0 = att + (size_t)r0 * (V * F);
  float* attb1 = att + (size_t)r1 * (V * F);
  const unsigned maL = ma32 >> jh;   // per-lane pre-shift: bit (2*jj) <-> j0+2*jj+jh
  const unsigned mbL = mb32 >> jh;

  if (!(ua | ub)) {
    // common path: no uniform rows (adj row fully masked ~never happens)
#pragma unroll 4
    for (int jj = 0; jj < 16; ++jj) {
      const int j = j0 + jj * 2 + jh;
      const float4 e2q = *reinterpret_cast<const float4*>(E2t + j * F + f4);
      const float ga = (float)((maL >> (2 * jj)) & 1u);
      const float gb = (float)((mbL >> (2 * jj)) & 1u);
      const float va0 = invqa.x * ga, va1 = invqa.y * ga, va2 = invqa.z * ga, va3 = invqa.w * ga;
      const float vb0 = invqb.x * gb, vb1 = invqb.y * gb, vb2 = invqb.z * gb, vb3 = invqb.w * gb;

      float x0 = e1qa.x + e2q.x, x1 = e1qa.y + e2q.y;
      float x2 = e1qa.z + e2q.z, x3 = e1qa.w + e2q.w;
      x0 = fmaxf(x0, ALPHA * x0); x1 = fmaxf(x1, ALPHA * x1);
      x2 = fmaxf(x2, ALPHA * x2); x3 = fmaxf(x3, ALPHA * x3);
      f32x4 o;
      o.x = __expf(x0) * va0; o.y = __expf(x1) * va1;
      o.z = __expf(x2) * va2; o.w = __expf(x3) * va3;
      __builtin_nontemporal_store(o, reinterpret_cast<f32x4*>(attb0 + j * F + f4));

      x0 = e1qb.x + e2q.x; x1 = e1qb.y + e2q.y;
      x2 = e1qb.z + e2q.z; x3 = e1qb.w + e2q.w;
      x0 = fmaxf(x0, ALPHA * x0); x1 = fmaxf(x1, ALPHA * x1);
      x2 = fmaxf(x2, ALPHA * x2); x3 = fmaxf(x3, ALPHA * x3);
      o.x = __expf(x0) * vb0; o.y = __expf(x1) * vb1;
      o.z = __expf(x2) * vb2; o.w = __expf(x3) * vb3;
      __builtin_nontemporal_store(o, reinterpret_cast<f32x4*>(attb1 + j * F + f4));
    }
  } else {
    // rare fallback: at least one row fully masked -> uniform 1/V attention
#pragma unroll 2
    for (int jj = 0; jj < 16; ++jj) {
      const int j = j0 + jj * 2 + jh;
      const float4 e2q = *reinterpret_cast<const float4*>(E2t + j * F + f4);
      const float ga = (float)((maL >> (2 * jj)) & 1u);
      const float gb = (float)((mbL >> (2 * jj)) & 1u);
      {
        float x0 = e1qa.x + e2q.x, x1 = e1qa.y + e2q.y;
        float x2 = e1qa.z + e2q.z, x3 = e1qa.w + e2q.w;
        x0 = fmaxf(x0, ALPHA * x0); x1 = fmaxf(x1, ALPHA * x1);
        x2 = fmaxf(x2, ALPHA * x2); x3 = fmaxf(x3, ALPHA * x3);
        float4 o;
        o.x = __expf(x0) * invqa.x * ga; o.y = __expf(x1) * invqa.y * ga;
        o.z = __expf(x2) * invqa.z * ga; o.w = __expf(x3) * invqa.w * ga;
        if (ua) { o.x = invqa.x; o.y = invqa.y; o.z = invqa.z; o.w = invqa.w; }
        *reinterpret_cast<float4*>(attb0 + j * F + f4) = o;
      }
      {
        float x0 = e1qb.x + e2q.x, x1 = e1qb.y + e2q.y;
        float x2 = e1qb.z + e2q.z, x3 = e1qb.w + e2q.w;
        x0 = fmaxf(x0, ALPHA * x0); x1 = fmaxf(x1, ALPHA * x1);
        x2 = fmaxf(x2, ALPHA * x2); x3 = fmaxf(x3, ALPHA * x3);
        float4 o;
        o.x = __expf(x0) * invqb.x * gb; o.y = __expf(x1) * invqb.y * gb;
        o.z = __expf(x2) * invqb.z * gb; o.w = __expf(x3) * invqb.w * gb;
        if (ub) { o.x = invqb.x; o.y = invqb.y; o.z = invqb.z; o.w = invqb.w; }
        *reinterpret_cast<float4*>(attb1 + j * F + f4) = o;
      }
    }
  }
}

extern "C" void kernel_launch(void* const* d_in, const int* in_sizes, int n_in,
                              void* d_out, int out_size, void* d_ws, size_t ws_size,
                              hipStream_t stream) {
  (void)in_sizes; (void)n_in; (void)out_size; (void)ws_size;
  const float* h   = (const float*)d_in[0];
  const float* adj = (const float*)d_in[1];
  const float* W   = (const float*)d_in[2];
  const float* a   = (const float*)d_in[3];

  float* Wh = (float*)d_ws;
  float* E1 = Wh + NTIME * V * F;
  float* E2 = E1 + NTIME * V * F;
  float* Wa = E2 + NTIME * V * F;

  float* out = (float*)d_out;                    // (T, V, F)
  float* att = out + NTIME * V * F;              // (T, V, V, F)

  k_wa<<<dim3(128, 2), 128, 0, stream>>>(W, a, Wa);
  k_gemm<<<dim3(80, 6), 256, 0, stream>>>(h, W, Wa, Wh, E1, E2);
  k_attn<<<dim3(NTIME * V / 2), 256, 0, stream>>>(Wh, E1, E2, adj, out, att);
}